// Round 3
// baseline (202.948 us; speedup 1.0000x reference)
//
#include <hip/hip_runtime.h>

#define B_SZ 8192
#define C_SZ 1024
#define NCLS 100
#define INV_T 0.25f
#define NTMAX 8
#define NTRI 36   // NTMAX*(NTMAX+1)/2
#define VITEMS (NCLS * NTRI)

typedef unsigned int uint32;

using bf16x8 = __attribute__((ext_vector_type(8))) short;
using f32x16 = __attribute__((ext_vector_type(16))) float;

// upper-triangular tile enumeration r -> (ti, tj), ti <= tj
__device__ __constant__ char TI_OF[NTRI] = {
    0, 0,1, 0,1,2, 0,1,2,3, 0,1,2,3,4, 0,1,2,3,4,5, 0,1,2,3,4,5,6, 0,1,2,3,4,5,6,7};
__device__ __constant__ char TJ_OF[NTRI] = {
    0, 1,1, 2,2,2, 3,3,3,3, 4,4,4,4,4, 5,5,5,5,5,5, 6,6,6,6,6,6,6, 7,7,7,7,7,7,7,7};

// round-to-nearest-even fp32 -> bf16 (inputs positive, finite)
__device__ __forceinline__ unsigned short f2bf(float f) {
    uint32 u = __float_as_uint(f);
    u = u + 0x7fffu + ((u >> 16) & 1u);
    return (unsigned short)(u >> 16);
}

__global__ __launch_bounds__(128) void init_kernel(int* meta) {
    meta[threadIdx.x] = 0;   // counts[0..99], accum, done all live in first 128 ints
}

// One block per row: softmax(x/T)+1e-8 -> bf16 probs; t[row]=mean(p log p);
// tid 0 also appends the row to its label bucket (fused bucket_kernel).
__global__ __launch_bounds__(256) void softmax_bucket_kernel(
        const float* __restrict__ x, const int* __restrict__ target,
        uint32* __restrict__ probs_bf, float* __restrict__ t,
        int* __restrict__ counts, int* __restrict__ lists) {
    int row = blockIdx.x;
    int tid = threadIdx.x;

    if (tid == 0) {   // bucket append, overlapped with the loads below
        int lbl = target[row];
        int slot = atomicAdd(&counts[lbl], 1);
        lists[lbl * B_SZ + slot] = row;
    }

    const float4* xr = (const float4*)(x + (size_t)row * C_SZ);
    float4 v = xr[tid];
    v.x *= INV_T; v.y *= INV_T; v.z *= INV_T; v.w *= INV_T;

    __shared__ float red[12];
    int wid = tid >> 6;

    float m = fmaxf(fmaxf(v.x, v.y), fmaxf(v.z, v.w));
    #pragma unroll
    for (int o = 32; o >= 1; o >>= 1) m = fmaxf(m, __shfl_xor(m, o, 64));
    if ((tid & 63) == 0) red[wid] = m;
    __syncthreads();
    m = fmaxf(fmaxf(red[0], red[1]), fmaxf(red[2], red[3]));

    float4 e;
    e.x = __expf(v.x - m); e.y = __expf(v.y - m);
    e.z = __expf(v.z - m); e.w = __expf(v.w - m);
    float s = (e.x + e.y) + (e.z + e.w);
    #pragma unroll
    for (int o = 32; o >= 1; o >>= 1) s += __shfl_xor(s, o, 64);
    if ((tid & 63) == 0) red[4 + wid] = s;
    __syncthreads();
    float Z = (red[4] + red[5]) + (red[6] + red[7]);
    float rZ = 1.0f / Z;

    float4 p;
    p.x = e.x * rZ + 1e-8f; p.y = e.y * rZ + 1e-8f;
    p.z = e.z * rZ + 1e-8f; p.w = e.w * rZ + 1e-8f;

    uint2 packed;
    packed.x = ((uint32)f2bf(p.y) << 16) | (uint32)f2bf(p.x);
    packed.y = ((uint32)f2bf(p.w) << 16) | (uint32)f2bf(p.z);
    ((uint2*)(probs_bf + (size_t)row * (C_SZ / 2)))[tid] = packed;

    float pl = p.x * __logf(p.x) + p.y * __logf(p.y) +
               p.z * __logf(p.z) + p.w * __logf(p.w);
    #pragma unroll
    for (int o = 32; o >= 1; o >>= 1) pl += __shfl_xor(pl, o, 64);
    if ((tid & 63) == 0) red[8 + wid] = pl;
    __syncthreads();
    if (tid == 0)
        t[row] = ((red[8] + red[9]) + (red[10] + red[11])) * (1.0f / C_SZ);
}

// One wave per 32x32 upper-triangular Gram tile, virtual enumeration over
// (class, tri-tile) -- no item table. Symmetry: off-diag tiles contribute both
// (t_j - c)^2 and (t_i - c)^2; diag tiles stage one strip (B aliases A).
// mfma_f32_32x32x16_bf16, D: col=lane&31, row=(reg&3)+8*(reg>>2)+4*(lane>>5).
// Last block to finish writes out[0] (fused finalize).
__global__ __launch_bounds__(64) void pair_kernel(const uint4* __restrict__ probs,
                                                  const float* __restrict__ t,
                                                  const int* __restrict__ counts,
                                                  const int* __restrict__ lists,
                                                  float* __restrict__ accum,
                                                  int* __restrict__ done,
                                                  float* __restrict__ out) {
    __shared__ uint4 tile[2 * 32 * 16];   // 2 strips x 32 rows x 16 chunks = 16 KB
    __shared__ int s_rid[2][32];          // [0]=A strip (i), [1]=B strip (j)
    __shared__ float s_t[2][32];

    int tid = threadIdx.x;

    for (int v = blockIdx.x; v < VITEMS; v += gridDim.x) {
        int k = v / NTRI;                 // compile-time magic-mul
        int r36 = v - k * NTRI;
        int ti = TI_OF[r36];
        int tj = TJ_OF[r36];
        int m = counts[k];
        int nt = (m + 31) >> 5;
        if (tj >= nt) continue;           // ti <= tj, so this covers both
        bool diag = (ti == tj);

        __syncthreads();                  // previous item fully done with LDS
        {
            int strip = tid >> 5;         // 0 = A(i), 1 = B(j)
            int l = tid & 31;
            int base = (strip ? tj : ti) * 32 + l;
            int w = base < m ? base : m - 1;     // clamp; masked in epilogue
            int rid = lists[k * B_SZ + w];
            s_rid[strip][l] = rid;
            s_t[strip][l] = t[rid];
        }
        __syncthreads();

        int nchunk_steps = diag ? 8 : 16;        // 512 or 1024 16B chunks / 64 thr
        int bbase = diag ? 0 : 512;              // B frag aliases A on diagonal

        f32x16 acc = {};
        #pragma unroll 1
        for (int ki = 0; ki < 8; ki++) {
            for (int s = 0; s < nchunk_steps; s++) {
                int idx = tid + s * 64;
                int strip = idx >> 9;
                int rr = (idx >> 4) & 31;
                int c = idx & 15;
                int rid = s_rid[strip][rr];
                uint4 vv = probs[(size_t)rid * (C_SZ / 8) + ki * 16 + c];
                tile[((strip * 32 + rr) << 4) + (c ^ (rr & 15))] = vv;
            }
            __syncthreads();
            int half = tid >> 5;
            int rr = tid & 31;
            #pragma unroll
            for (int i = 0; i < 8; i++) {
                int ch = (2 * i + half) ^ (rr & 15);
                bf16x8 a = *(const bf16x8*)&tile[(rr << 4) + ch];
                bf16x8 b = *(const bf16x8*)&tile[bbase + (rr << 4) + ch];
                acc = __builtin_amdgcn_mfma_f32_32x32x16_bf16(a, b, acc, 0, 0, 0);
            }
            __syncthreads();
        }

        // epilogue
        int col = tid & 31;
        int jl = tj * 32 + col;
        bool jv = jl < m;
        float tjv = s_t[1][col];
        float local = 0.0f;
        #pragma unroll
        for (int g = 0; g < 16; g++) {
            int rowloc = (g & 3) + 8 * (g >> 2) + 4 * (tid >> 5);
            int il = ti * 32 + rowloc;
            if (jv && il < m) {
                float c = acc[g] * (1.0f / C_SZ);
                if (diag) {
                    if (il != jl) { float d = tjv - c; local += d * d; }
                } else {
                    float d1 = tjv - c;
                    float d2 = s_t[0][rowloc] - c;
                    local += d1 * d1 + d2 * d2;
                }
            }
        }
        #pragma unroll
        for (int o = 32; o >= 1; o >>= 1) local += __shfl_xor(local, o, 64);
        if (tid == 0 && local != 0.0f) atomicAdd(accum, local);
    }

    // fused finalize: last block to arrive publishes the result
    if (tid == 0) {
        __threadfence();
        int ticket = atomicAdd(done, 1);
        if (ticket == (int)gridDim.x - 1) {
            float a = atomicAdd(accum, 0.0f);   // device-scope coherent read
            out[0] = a * (1.0f / B_SZ);
        }
    }
}

extern "C" void kernel_launch(void* const* d_in, const int* in_sizes, int n_in,
                              void* d_out, int out_size, void* d_ws, size_t ws_size,
                              hipStream_t stream) {
    const float* x = (const float*)d_in[0];
    const int* target = (const int*)d_in[1];
    float* out = (float*)d_out;

    char* ws = (char*)d_ws;
    uint32* probs_bf = (uint32*)ws;                                 // 16 MB
    char* p = ws + (size_t)B_SZ * C_SZ * 2;
    float* t = (float*)p;        p += B_SZ * 4;                     // 32 KB
    int* meta = (int*)p;         p += 128 * 4;                      // counts+accum+done
    int* counts = meta;                                             // [0..99]
    float* accum = (float*)(meta + 100);
    int* done = meta + 101;
    int* lists = (int*)p;                                           // 3.2 MB

    init_kernel<<<1, 128, 0, stream>>>(meta);
    softmax_bucket_kernel<<<B_SZ, 256, 0, stream>>>(x, target, probs_bf, t,
                                                    counts, lists);
    pair_kernel<<<1024, 64, 0, stream>>>((const uint4*)probs_bf, t, counts, lists,
                                         accum, done, out);
}

// Round 4
// 149.299 us; speedup vs baseline: 1.3593x; 1.3593x over previous
//
#include <hip/hip_runtime.h>

#define B_SZ 8192
#define C_SZ 1024
#define NCLS 100
#define INV_T 0.25f
#define NTRI 36   // 8*(8+1)/2 upper-triangular tiles max (m <= 256 per class)
#define VITEMS (NCLS * NTRI)

typedef unsigned int uint32;

using bf16x8 = __attribute__((ext_vector_type(8))) short;
using f32x16 = __attribute__((ext_vector_type(16))) float;

// upper-triangular tile enumeration r -> (ti, tj), ti <= tj, ordered by tj:
// valid entries for a class with nt tiles are exactly r < nt*(nt+1)/2.
__device__ __constant__ char TI_OF[NTRI] = {
    0, 0,1, 0,1,2, 0,1,2,3, 0,1,2,3,4, 0,1,2,3,4,5, 0,1,2,3,4,5,6, 0,1,2,3,4,5,6,7};
__device__ __constant__ char TJ_OF[NTRI] = {
    0, 1,1, 2,2,2, 3,3,3,3, 4,4,4,4,4, 5,5,5,5,5,5, 6,6,6,6,6,6,6, 7,7,7,7,7,7,7,7};

// round-to-nearest-even fp32 -> bf16 (inputs positive, finite)
__device__ __forceinline__ unsigned short f2bf(float f) {
    uint32 u = __float_as_uint(f);
    u = u + 0x7fffu + ((u >> 16) & 1u);
    return (unsigned short)(u >> 16);
}

__global__ __launch_bounds__(128) void init_kernel(int* meta) {
    meta[threadIdx.x] = 0;   // counts[0..99], accum, done
}

// One block per row: softmax(x/T)+1e-8 -> bf16 probs; t[row]=mean(p log p);
// tid 0 appends the row to its label bucket.
__global__ __launch_bounds__(256) void softmax_bucket_kernel(
        const float* __restrict__ x, const int* __restrict__ target,
        uint32* __restrict__ probs_bf, float* __restrict__ t,
        int* __restrict__ counts, int* __restrict__ lists) {
    int row = blockIdx.x;
    int tid = threadIdx.x;

    if (tid == 0) {
        int lbl = target[row];
        int slot = atomicAdd(&counts[lbl], 1);
        lists[lbl * B_SZ + slot] = row;
    }

    const float4* xr = (const float4*)(x + (size_t)row * C_SZ);
    float4 v = xr[tid];
    v.x *= INV_T; v.y *= INV_T; v.z *= INV_T; v.w *= INV_T;

    __shared__ float red[12];
    int wid = tid >> 6;

    float m = fmaxf(fmaxf(v.x, v.y), fmaxf(v.z, v.w));
    #pragma unroll
    for (int o = 32; o >= 1; o >>= 1) m = fmaxf(m, __shfl_xor(m, o, 64));
    if ((tid & 63) == 0) red[wid] = m;
    __syncthreads();
    m = fmaxf(fmaxf(red[0], red[1]), fmaxf(red[2], red[3]));

    float4 e;
    e.x = __expf(v.x - m); e.y = __expf(v.y - m);
    e.z = __expf(v.z - m); e.w = __expf(v.w - m);
    float s = (e.x + e.y) + (e.z + e.w);
    #pragma unroll
    for (int o = 32; o >= 1; o >>= 1) s += __shfl_xor(s, o, 64);
    if ((tid & 63) == 0) red[4 + wid] = s;
    __syncthreads();
    float Z = (red[4] + red[5]) + (red[6] + red[7]);
    float rZ = 1.0f / Z;

    float4 p;
    p.x = e.x * rZ + 1e-8f; p.y = e.y * rZ + 1e-8f;
    p.z = e.z * rZ + 1e-8f; p.w = e.w * rZ + 1e-8f;

    uint2 packed;
    packed.x = ((uint32)f2bf(p.y) << 16) | (uint32)f2bf(p.x);
    packed.y = ((uint32)f2bf(p.w) << 16) | (uint32)f2bf(p.z);
    ((uint2*)(probs_bf + (size_t)row * (C_SZ / 2)))[tid] = packed;

    float pl = p.x * __logf(p.x) + p.y * __logf(p.y) +
               p.z * __logf(p.z) + p.w * __logf(p.w);
    #pragma unroll
    for (int o = 32; o >= 1; o >>= 1) pl += __shfl_xor(pl, o, 64);
    if ((tid & 63) == 0) red[8 + wid] = pl;
    __syncthreads();
    if (tid == 0)
        t[row] = ((red[8] + red[9]) + (red[10] + red[11])) * (1.0f / C_SZ);
}

// One WAVE per 32x32 upper-triangular Gram tile. NO LDS: mfma_f32_32x32x16_bf16
// A/B fragments are per-lane 16B contiguous (row = lane&31, kbase = (lane>>5)*8),
// so each lane loads its fragment straight from global (L2-resident rows).
// 4 independent waves per block hide each other's load latency.
// D layout: col=lane&31, row=(reg&3)+8*(reg>>2)+4*(lane>>5).
// Symmetry: off-diag tile contributes (t_j-c)^2 + (t_i-c)^2.
// Last wave to finish publishes out[0].
__global__ __launch_bounds__(256) void pair_kernel(const char* __restrict__ probs,
                                                   const float* __restrict__ t,
                                                   const int* __restrict__ counts,
                                                   const int* __restrict__ lists,
                                                   float* __restrict__ accum,
                                                   int* __restrict__ done,
                                                   float* __restrict__ out) {
    int tid = threadIdx.x & 63;
    int wave = blockIdx.x * 4 + (threadIdx.x >> 6);
    int nwaves = gridDim.x * 4;
    int lane5 = tid & 31;
    int half = tid >> 5;

    float total = 0.0f;

    for (int v = wave; v < VITEMS; v += nwaves) {
        int k = v / NTRI;                 // magic-mul (compile-time const divisor)
        int r36 = v - k * NTRI;
        int m = counts[k];                // wave-uniform scalar load
        int nt = (m + 31) >> 5;
        int tj = TJ_OF[r36];
        if (tj >= nt) continue;
        int ti = TI_OF[r36];
        bool diag = (ti == tj);

        int ia = ti * 32 + lane5;
        int ib = tj * 32 + lane5;
        int ridA = lists[k * B_SZ + (ia < m ? ia : m - 1)];
        int ridB = lists[k * B_SZ + (ib < m ? ib : m - 1)];
        float tA = t[ridA];
        float tB = t[ridB];

        const char* baseA = probs + (size_t)ridA * (C_SZ * 2) + half * 16;
        const char* baseB = probs + (size_t)ridB * (C_SZ * 2) + half * 16;

        f32x16 acc = {};
        #pragma unroll 8
        for (int kk = 0; kk < 64; kk++) {
            bf16x8 a = *(const bf16x8*)(baseA + kk * 32);
            bf16x8 b = *(const bf16x8*)(baseB + kk * 32);
            acc = __builtin_amdgcn_mfma_f32_32x32x16_bf16(a, b, acc, 0, 0, 0);
        }

        bool jv = ib < m;
        #pragma unroll
        for (int g = 0; g < 16; g++) {
            int rowloc = (g & 3) + 8 * (g >> 2) + 4 * half;
            int il = ti * 32 + rowloc;
            float tAr = __shfl(tA, rowloc, 32);   // t of A-strip row `rowloc`
            if (jv && il < m) {
                float c = acc[g] * (1.0f / C_SZ);
                if (diag) {
                    if (il != ib) { float d = tB - c; total += d * d; }
                } else {
                    float d1 = tB - c;
                    float d2 = tAr - c;
                    total += d1 * d1 + d2 * d2;
                }
            }
        }
    }

    #pragma unroll
    for (int o = 32; o >= 1; o >>= 1) total += __shfl_xor(total, o, 64);
    if (tid == 0) {
        if (total != 0.0f) atomicAdd(accum, total);
        __threadfence();
        int ticket = atomicAdd(done, 1);
        if (ticket == nwaves - 1) {
            float a = atomicAdd(accum, 0.0f);     // device-scope coherent read
            out[0] = a * (1.0f / B_SZ);
        }
    }
}

extern "C" void kernel_launch(void* const* d_in, const int* in_sizes, int n_in,
                              void* d_out, int out_size, void* d_ws, size_t ws_size,
                              hipStream_t stream) {
    const float* x = (const float*)d_in[0];
    const int* target = (const int*)d_in[1];
    float* out = (float*)d_out;

    char* ws = (char*)d_ws;
    uint32* probs_bf = (uint32*)ws;                                 // 16 MB
    char* p = ws + (size_t)B_SZ * C_SZ * 2;
    float* t = (float*)p;        p += B_SZ * 4;                     // 32 KB
    int* meta = (int*)p;         p += 128 * 4;                      // counts+accum+done
    int* counts = meta;
    float* accum = (float*)(meta + 100);
    int* done = meta + 101;
    int* lists = (int*)p;                                           // 3.2 MB

    init_kernel<<<1, 128, 0, stream>>>(meta);
    softmax_bucket_kernel<<<B_SZ, 256, 0, stream>>>(x, target, probs_bf, t,
                                                    counts, lists);
    pair_kernel<<<256, 256, 0, stream>>>((const char*)probs_bf, t, counts, lists,
                                         accum, done, out);
}

// Round 5
// 148.390 us; speedup vs baseline: 1.3677x; 1.0061x over previous
//
#include <hip/hip_runtime.h>

#define B_SZ 8192
#define C_SZ 1024
#define NCLS 100
#define INV_T 0.25f
#define NTRI 36   // 8*(8+1)/2 upper-triangular tiles max (m <= 256 per class)
#define VITEMS (NCLS * NTRI)

typedef unsigned int uint32;

using bf16x8 = __attribute__((ext_vector_type(8))) short;
using f32x16 = __attribute__((ext_vector_type(16))) float;

// upper-triangular tile enumeration r -> (ti, tj), ti <= tj, ordered by tj:
// valid entries for a class with nt tiles are exactly r < nt*(nt+1)/2.
__device__ __constant__ char TI_OF[NTRI] = {
    0, 0,1, 0,1,2, 0,1,2,3, 0,1,2,3,4, 0,1,2,3,4,5, 0,1,2,3,4,5,6, 0,1,2,3,4,5,6,7};
__device__ __constant__ char TJ_OF[NTRI] = {
    0, 1,1, 2,2,2, 3,3,3,3, 4,4,4,4,4, 5,5,5,5,5,5, 6,6,6,6,6,6,6, 7,7,7,7,7,7,7,7};

// round-to-nearest-even fp32 -> bf16 (inputs positive, finite)
__device__ __forceinline__ unsigned short f2bf(float f) {
    uint32 u = __float_as_uint(f);
    u = u + 0x7fffu + ((u >> 16) & 1u);
    return (unsigned short)(u >> 16);
}

__global__ __launch_bounds__(128) void init_kernel(int* meta) {
    meta[threadIdx.x] = 0;   // counts[0..99], accum, done
}

// One block per row: softmax(x/T)+1e-8 -> bf16 probs; t[row]=mean(p log p);
// tid 0 appends the row to its label bucket.
__global__ __launch_bounds__(256) void softmax_bucket_kernel(
        const float* __restrict__ x, const int* __restrict__ target,
        uint32* __restrict__ probs_bf, float* __restrict__ t,
        int* __restrict__ counts, int* __restrict__ lists) {
    int row = blockIdx.x;
    int tid = threadIdx.x;

    if (tid == 0) {
        int lbl = target[row];
        int slot = atomicAdd(&counts[lbl], 1);
        lists[lbl * B_SZ + slot] = row;
    }

    const float4* xr = (const float4*)(x + (size_t)row * C_SZ);
    float4 v = xr[tid];
    v.x *= INV_T; v.y *= INV_T; v.z *= INV_T; v.w *= INV_T;

    __shared__ float red[12];
    int wid = tid >> 6;

    float m = fmaxf(fmaxf(v.x, v.y), fmaxf(v.z, v.w));
    #pragma unroll
    for (int o = 32; o >= 1; o >>= 1) m = fmaxf(m, __shfl_xor(m, o, 64));
    if ((tid & 63) == 0) red[wid] = m;
    __syncthreads();
    m = fmaxf(fmaxf(red[0], red[1]), fmaxf(red[2], red[3]));

    float4 e;
    e.x = __expf(v.x - m); e.y = __expf(v.y - m);
    e.z = __expf(v.z - m); e.w = __expf(v.w - m);
    float s = (e.x + e.y) + (e.z + e.w);
    #pragma unroll
    for (int o = 32; o >= 1; o >>= 1) s += __shfl_xor(s, o, 64);
    if ((tid & 63) == 0) red[4 + wid] = s;
    __syncthreads();
    float Z = (red[4] + red[5]) + (red[6] + red[7]);
    float rZ = 1.0f / Z;

    float4 p;
    p.x = e.x * rZ + 1e-8f; p.y = e.y * rZ + 1e-8f;
    p.z = e.z * rZ + 1e-8f; p.w = e.w * rZ + 1e-8f;

    uint2 packed;
    packed.x = ((uint32)f2bf(p.y) << 16) | (uint32)f2bf(p.x);
    packed.y = ((uint32)f2bf(p.w) << 16) | (uint32)f2bf(p.z);
    ((uint2*)(probs_bf + (size_t)row * (C_SZ / 2)))[tid] = packed;

    float pl = p.x * __logf(p.x) + p.y * __logf(p.y) +
               p.z * __logf(p.z) + p.w * __logf(p.w);
    #pragma unroll
    for (int o = 32; o >= 1; o >>= 1) pl += __shfl_xor(pl, o, 64);
    if ((tid & 63) == 0) red[8 + wid] = pl;
    __syncthreads();
    if (tid == 0)
        t[row] = ((red[8] + red[9]) + (red[10] + red[11])) * (1.0f / C_SZ);
}

// One WAVE per 32x32 upper-triangular Gram tile, fragments loaded straight from
// global (no LDS). Explicit double-buffered load groups (a1/b1 prefetched while
// a0/b0 feed MFMA) so 16 global_load_dwordx4 stay in flight -- R4's compiler
// chose VGPR=40 and serialized every load; the 4-array structure + (256,1)
// launch bounds forces pipelining.
// mfma_f32_32x32x16_bf16 A/B frag: row=lane&31, kbase=(lane>>5)*8 -> 16B/lane.
// D: col=lane&31, row=(reg&3)+8*(reg>>2)+4*(lane>>5).
__global__ __launch_bounds__(256, 1) void pair_kernel(
        const char* __restrict__ probs, const float* __restrict__ t,
        const int* __restrict__ counts, const int* __restrict__ lists,
        float* __restrict__ accum, int* __restrict__ done,
        float* __restrict__ out) {
    int tid = threadIdx.x & 63;
    int wave = blockIdx.x * 4 + (threadIdx.x >> 6);
    int nwaves = gridDim.x * 4;
    int lane5 = tid & 31;
    int half = tid >> 5;

    float total = 0.0f;

    for (int v = wave; v < VITEMS; v += nwaves) {
        int k = v / NTRI;                 // magic-mul (compile-time const divisor)
        int r36 = v - k * NTRI;
        int m = counts[k];                // wave-uniform scalar load
        int nt = (m + 31) >> 5;
        int tj = TJ_OF[r36];
        if (tj >= nt) continue;
        int ti = TI_OF[r36];
        bool diag = (ti == tj);

        int ia = ti * 32 + lane5;
        int ib = tj * 32 + lane5;
        int ridA = lists[k * B_SZ + (ia < m ? ia : m - 1)];
        int ridB = lists[k * B_SZ + (ib < m ? ib : m - 1)];
        float tA = t[ridA];
        float tB = t[ridB];

        const char* baseA = probs + (size_t)ridA * (C_SZ * 2) + half * 16;
        const char* baseB = probs + (size_t)ridB * (C_SZ * 2) + half * 16;

        f32x16 acc = {};
        bf16x8 a0[8], b0[8], a1[8], b1[8];
        #pragma unroll
        for (int u = 0; u < 8; u++) {
            a0[u] = *(const bf16x8*)(baseA + u * 32);
            b0[u] = *(const bf16x8*)(baseB + u * 32);
        }
        #pragma unroll
        for (int g = 0; g < 8; g++) {
            if (g < 7) {
                #pragma unroll
                for (int u = 0; u < 8; u++) {
                    a1[u] = *(const bf16x8*)(baseA + ((g + 1) * 8 + u) * 32);
                    b1[u] = *(const bf16x8*)(baseB + ((g + 1) * 8 + u) * 32);
                }
            }
            #pragma unroll
            for (int u = 0; u < 8; u++)
                acc = __builtin_amdgcn_mfma_f32_32x32x16_bf16(a0[u], b0[u], acc, 0, 0, 0);
            #pragma unroll
            for (int u = 0; u < 8; u++) { a0[u] = a1[u]; b0[u] = b1[u]; }
        }

        bool jv = ib < m;
        #pragma unroll
        for (int g = 0; g < 16; g++) {
            int rowloc = (g & 3) + 8 * (g >> 2) + 4 * half;
            int il = ti * 32 + rowloc;
            float tAr = __shfl(tA, rowloc, 32);   // t of A-strip row `rowloc`
            if (jv && il < m) {
                float c = acc[g] * (1.0f / C_SZ);
                if (diag) {
                    if (il != ib) { float d = tB - c; total += d * d; }
                } else {
                    float d1 = tB - c;
                    float d2 = tAr - c;
                    total += d1 * d1 + d2 * d2;
                }
            }
        }
    }

    #pragma unroll
    for (int o = 32; o >= 1; o >>= 1) total += __shfl_xor(total, o, 64);
    if (tid == 0) {
        if (total != 0.0f) atomicAdd(accum, total);
        __threadfence();
        int ticket = atomicAdd(done, 1);
        if (ticket == nwaves - 1) {
            float a = atomicAdd(accum, 0.0f);     // device-scope coherent read
            out[0] = a * (1.0f / B_SZ);
        }
    }
}

extern "C" void kernel_launch(void* const* d_in, const int* in_sizes, int n_in,
                              void* d_out, int out_size, void* d_ws, size_t ws_size,
                              hipStream_t stream) {
    const float* x = (const float*)d_in[0];
    const int* target = (const int*)d_in[1];
    float* out = (float*)d_out;

    char* ws = (char*)d_ws;
    uint32* probs_bf = (uint32*)ws;                                 // 16 MB
    char* p = ws + (size_t)B_SZ * C_SZ * 2;
    float* t = (float*)p;        p += B_SZ * 4;                     // 32 KB
    int* meta = (int*)p;         p += 128 * 4;                      // counts+accum+done
    int* counts = meta;
    float* accum = (float*)(meta + 100);
    int* done = meta + 101;
    int* lists = (int*)p;                                           // 3.2 MB

    init_kernel<<<1, 128, 0, stream>>>(meta);
    softmax_bucket_kernel<<<B_SZ, 256, 0, stream>>>(x, target, probs_bf, t,
                                                    counts, lists);
    pair_kernel<<<256, 256, 0, stream>>>((const char*)probs_bf, t, counts, lists,
                                         accum, done, out);
}

// Round 6
// 135.668 us; speedup vs baseline: 1.4959x; 1.0938x over previous
//
#include <hip/hip_runtime.h>

#define B_SZ 8192
#define C_SZ 1024
#define NCLS 100
#define INV_T 0.25f
#define MAXTRI 21        // nt<=6 -> up to 21 upper-triangular tiles (m <= 192)
#define NQ 16            // 16B units per row per K-chunk (128 cols)
#define NCHUNK 8         // 1024 / 128
#define RSTRIDE 17       // 16B units per row in LDS (16 + 1 pad -> conflict-free)
#define BUFU (192 * RSTRIDE)

typedef unsigned int uint32;

using bf16x8 = __attribute__((ext_vector_type(8))) short;
using f32x16 = __attribute__((ext_vector_type(16))) float;

// upper-triangular tile idx -> (ti, tj), ti <= tj, grouped by tj:
// valid tiles for nt strips are exactly idx < nt*(nt+1)/2.
__device__ __constant__ char TI_OF[MAXTRI] = {
    0, 0,1, 0,1,2, 0,1,2,3, 0,1,2,3,4, 0,1,2,3,4,5};
__device__ __constant__ char TJ_OF[MAXTRI] = {
    0, 1,1, 2,2,2, 3,3,3,3, 4,4,4,4,4, 5,5,5,5,5,5};

// round-to-nearest-even fp32 -> bf16 (inputs positive, finite)
__device__ __forceinline__ unsigned short f2bf(float f) {
    uint32 u = __float_as_uint(f);
    u = u + 0x7fffu + ((u >> 16) & 1u);
    return (unsigned short)(u >> 16);
}

__global__ __launch_bounds__(128) void init_kernel(int* meta) {
    meta[threadIdx.x] = 0;   // counts[0..99], accum, done
}

// One block per row: softmax(x/T)+1e-8 -> bf16 probs; t[row]=mean(p log p);
// tid 0 appends the row to its label bucket.
__global__ __launch_bounds__(256) void softmax_bucket_kernel(
        const float* __restrict__ x, const int* __restrict__ target,
        uint32* __restrict__ probs_bf, float* __restrict__ t,
        int* __restrict__ counts, int* __restrict__ lists) {
    int row = blockIdx.x;
    int tid = threadIdx.x;

    if (tid == 0) {
        int lbl = target[row];
        int slot = atomicAdd(&counts[lbl], 1);
        lists[lbl * B_SZ + slot] = row;
    }

    const float4* xr = (const float4*)(x + (size_t)row * C_SZ);
    float4 v = xr[tid];
    v.x *= INV_T; v.y *= INV_T; v.z *= INV_T; v.w *= INV_T;

    __shared__ float red[12];
    int wid = tid >> 6;

    float m = fmaxf(fmaxf(v.x, v.y), fmaxf(v.z, v.w));
    #pragma unroll
    for (int o = 32; o >= 1; o >>= 1) m = fmaxf(m, __shfl_xor(m, o, 64));
    if ((tid & 63) == 0) red[wid] = m;
    __syncthreads();
    m = fmaxf(fmaxf(red[0], red[1]), fmaxf(red[2], red[3]));

    float4 e;
    e.x = __expf(v.x - m); e.y = __expf(v.y - m);
    e.z = __expf(v.z - m); e.w = __expf(v.w - m);
    float s = (e.x + e.y) + (e.z + e.w);
    #pragma unroll
    for (int o = 32; o >= 1; o >>= 1) s += __shfl_xor(s, o, 64);
    if ((tid & 63) == 0) red[4 + wid] = s;
    __syncthreads();
    float Z = (red[4] + red[5]) + (red[6] + red[7]);
    float rZ = 1.0f / Z;

    float4 p;
    p.x = e.x * rZ + 1e-8f; p.y = e.y * rZ + 1e-8f;
    p.z = e.z * rZ + 1e-8f; p.w = e.w * rZ + 1e-8f;

    uint2 packed;
    packed.x = ((uint32)f2bf(p.y) << 16) | (uint32)f2bf(p.x);
    packed.y = ((uint32)f2bf(p.w) << 16) | (uint32)f2bf(p.z);
    ((uint2*)(probs_bf + (size_t)row * (C_SZ / 2)))[tid] = packed;

    float pl = p.x * __logf(p.x) + p.y * __logf(p.y) +
               p.z * __logf(p.z) + p.w * __logf(p.w);
    #pragma unroll
    for (int o = 32; o >= 1; o >>= 1) pl += __shfl_xor(pl, o, 64);
    if ((tid & 63) == 0) red[8 + wid] = pl;
    __syncthreads();
    if (tid == 0)
        t[row] = ((red[8] + red[9]) + (red[10] + red[11])) * (1.0f / C_SZ);
}

// ONE BLOCK PER CLASS. All m rows (<=192, 12 sigma above binomial mean 82) are
// staged once per 128-col K-chunk into double-buffered LDS; the nt*(nt+1)/2
// 32x32 tri-tiles of the class Gram matrix read fragments from LDS and
// accumulate in persistent per-wave MFMA accumulators. Staging loads are
// compile-time-unrolled (wave-uniform nt guards, no runtime trip counts) and
// issue before the chunk's MFMA work so they overlap compute across 4 waves.
// mfma_f32_32x32x16_bf16 A/B frag: row=lane&31, kbase=(lane>>5)*8 (16B/lane).
// D: col=lane&31, row=(reg&3)+8*(reg>>2)+4*(lane>>5).
// Off-diag tiles (ti<tj) contribute (t_j-c)^2 + (t_i-c)^2 (Gram symmetry).
__global__ __launch_bounds__(256, 1) void pair_kernel(
        const char* __restrict__ probs, const float* __restrict__ t,
        const int* __restrict__ counts, const int* __restrict__ lists,
        float* __restrict__ accum, int* __restrict__ done,
        float* __restrict__ out) {
    __shared__ uint4 lds[2 * BUFU];      // ~102 KB
    __shared__ int s_rid[192];
    __shared__ float s_t[192];
    __shared__ float s_part[4];

    const int tid = threadIdx.x;
    const int k = blockIdx.x;
    const int lane = tid & 63;
    const int wid = tid >> 6;
    const int lane5 = lane & 31;
    const int half = lane >> 5;

    const int m = counts[k];
    float total = 0.0f;

    if (m > 0) {
        const int nt = (m + 31) >> 5;            // strips (<= 6)
        const int T = nt * (nt + 1) / 2;         // tri-tiles

        if (tid < 192) {
            int w = tid < m ? tid : m - 1;       // clamp; masked in epilogue
            int rid = lists[k * B_SZ + w];
            s_rid[tid] = rid;
            s_t[tid] = t[rid];
        }
        __syncthreads();

        // unit i*256+tid covers (row r = i*16 + (tid>>4), q = tid&15)
        int ridreg[12];
        #pragma unroll
        for (int i = 0; i < 12; i++) ridreg[i] = s_rid[(i * 256 + tid) >> 4];
        const int q = tid & 15;
        const int rof = tid >> 4;

        uint4 regs[12];
        f32x16 acc[6] = {};

        #define LOADI(i, c) regs[i] = *(const uint4*)(probs + \
            (size_t)ridreg[i] * (C_SZ * 2) + (c) * (NQ * 16) + q * 16)
        #define STORI(i, bsel) lds[(bsel) * BUFU + ((i) * 16 + rof) * RSTRIDE + q] = regs[i]
        #define LOAD2(p, c)  { LOADI(2*(p), c); LOADI(2*(p)+1, c); }
        #define STOR2(p, b)  { STORI(2*(p), b); STORI(2*(p)+1, b); }
        #define LOADALL(c) { LOAD2(0, c); if (nt > 1) LOAD2(1, c); if (nt > 2) LOAD2(2, c); \
                             if (nt > 3) LOAD2(3, c); if (nt > 4) LOAD2(4, c); if (nt > 5) LOAD2(5, c); }
        #define STORALL(b) { STOR2(0, b); if (nt > 1) STOR2(1, b); if (nt > 2) STOR2(2, b); \
                             if (nt > 3) STOR2(3, b); if (nt > 4) STOR2(4, b); if (nt > 5) STOR2(5, b); }

        LOADALL(0);
        STORALL(0);
        __syncthreads();

        #pragma unroll 1
        for (int c = 0; c < NCHUNK; c++) {
            if (c < NCHUNK - 1) LOADALL(c + 1);          // issue early, overlap MFMA
            const int bb = (c & 1) * BUFU;
            #pragma unroll
            for (int z = 0; z < 6; z++) {
                int tw = wid + z * 4;
                if (tw < T) {
                    int ti = TI_OF[tw], tj = TJ_OF[tw];
                    int abase = bb + (ti * 32 + lane5) * RSTRIDE + half;
                    int bbase = bb + (tj * 32 + lane5) * RSTRIDE + half;
                    #pragma unroll
                    for (int kk = 0; kk < 8; kk++) {
                        bf16x8 av = *(const bf16x8*)&lds[abase + kk * 2];
                        bf16x8 bv = *(const bf16x8*)&lds[bbase + kk * 2];
                        acc[z] = __builtin_amdgcn_mfma_f32_32x32x16_bf16(av, bv, acc[z], 0, 0, 0);
                    }
                }
            }
            if (c < NCHUNK - 1) STORALL((c + 1) & 1);
            __syncthreads();
        }

        const float invC = 1.0f / C_SZ;
        #pragma unroll
        for (int z = 0; z < 6; z++) {
            int tw = wid + z * 4;
            if (tw < T) {
                int ti = TI_OF[tw], tj = TJ_OF[tw];
                int jl = tj * 32 + lane5;
                bool jv = jl < m;
                float tB = s_t[jl];
                #pragma unroll
                for (int g = 0; g < 16; g++) {
                    int rowloc = (g & 3) + 8 * (g >> 2) + 4 * half;
                    int il = ti * 32 + rowloc;
                    if (jv && il < m) {
                        float cc = acc[z][g] * invC;
                        if (ti == tj) {
                            if (il != jl) { float d = tB - cc; total += d * d; }
                        } else {
                            float d1 = tB - cc;
                            float d2 = s_t[il] - cc;
                            total += d1 * d1 + d2 * d2;
                        }
                    }
                }
            }
        }
    }

    #pragma unroll
    for (int o = 32; o >= 1; o >>= 1) total += __shfl_xor(total, o, 64);
    if ((tid & 63) == 0) s_part[wid] = total;
    __syncthreads();
    if (tid == 0) {
        float bsum = (s_part[0] + s_part[1]) + (s_part[2] + s_part[3]);
        if (bsum != 0.0f) atomicAdd(accum, bsum);
        __threadfence();
        int ticket = atomicAdd(done, 1);
        if (ticket == NCLS - 1) {
            float a = atomicAdd(accum, 0.0f);    // device-scope coherent read
            out[0] = a * (1.0f / B_SZ);
        }
    }
}

extern "C" void kernel_launch(void* const* d_in, const int* in_sizes, int n_in,
                              void* d_out, int out_size, void* d_ws, size_t ws_size,
                              hipStream_t stream) {
    const float* x = (const float*)d_in[0];
    const int* target = (const int*)d_in[1];
    float* out = (float*)d_out;

    char* ws = (char*)d_ws;
    uint32* probs_bf = (uint32*)ws;                                 // 16 MB
    char* p = ws + (size_t)B_SZ * C_SZ * 2;
    float* t = (float*)p;        p += B_SZ * 4;                     // 32 KB
    int* meta = (int*)p;         p += 128 * 4;                      // counts+accum+done
    int* counts = meta;
    float* accum = (float*)(meta + 100);
    int* done = meta + 101;
    int* lists = (int*)p;                                           // 3.2 MB

    init_kernel<<<1, 128, 0, stream>>>(meta);
    softmax_bucket_kernel<<<B_SZ, 256, 0, stream>>>(x, target, probs_bf, t,
                                                    counts, lists);
    pair_kernel<<<NCLS, 256, 0, stream>>>((const char*)probs_bf, t, counts, lists,
                                          accum, done, out);
}